// Round 4
// baseline (259.735 us; speedup 1.0000x reference)
//
#include <hip/hip_runtime.h>
#include <hip/hip_bf16.h>
#include <math.h>

#define BB 8
#define CC 256
#define HH 128
#define WW 128
#define NN 4096
#define EE 128

typedef __bf16 bf16x8 __attribute__((ext_vector_type(8)));
typedef float f32x4 __attribute__((ext_vector_type(4)));

// ---- workspace layout (bytes) ----
#define WF_OFF    0          // __bf16[8][8][64][8]        = 64 KiB  (W, A-frag order)
#define DESCF_OFF 65536      // __bf16[BB][256][8][64][8]  = 16 MiB  (desc, B-frag order)
#define WS_NEED   (65536ull + 16777216ull)

// Streaming gather: 256 blocks (1/CU, 128 KiB LDS), each owns 8 planes of one
// batch. Depth-3 register pipeline keeps HBM busy; per-point results for the
// 8 planes accumulate in one bf16x8 register -> coalesced dwordx4 stores in
// exact MFMA B-fragment order. Also computes bilinear coefs in-kernel and
// emits Wf (W in A-frag order) as a side job.
__global__ __launch_bounds__(512, 2) void gather_kernel(
    const float* __restrict__ x, const float* __restrict__ kpts,
    const float* __restrict__ W, __bf16* __restrict__ descf,
    __bf16* __restrict__ Wf) {
  __shared__ float buf[2][HH * WW];   // 2 x 64 KiB = 128 KiB
  int blk = blockIdx.x;               // b*32 + g ; planes c = g*8 .. g*8+7
  int b = blk >> 5, g = blk & 31;
  int t = threadIdx.x;
  const float4* x4 = (const float4*)(x + ((size_t)((b << 8) + (g << 3)) << 14));
  // preload planes 0 and 1 into two register sets
  float4 r0[8], r1[8];
#pragma unroll
  for (int q = 0; q < 8; ++q) r0[q] = x4[t + 512 * q];
#pragma unroll
  for (int q = 0; q < 8; ++q) r1[q] = x4[4096 + t + 512 * q];
  // --- W fragment side job (hidden under plane staging) ---
  if (t < 128) {
    int i = (blk << 7) + t;
    int j = i & 7, lane = (i >> 3) & 63, etile = (i >> 9) & 7, kstep = (i >> 12) & 7;
    Wf[i] = (__bf16)W[(etile * 16 + (lane & 15)) * CC + kstep * 32 + ((lane >> 4) << 3) + j];
  }
  // --- bilinear coefs for this thread's 8 points (hidden under staging) ---
  int base[8];
  float4 wt[8];
  const float2* kp = (const float2*)(kpts + ((size_t)(b * NN) << 1));
#pragma unroll
  for (int i = 0; i < 8; ++i) {
    int n = t + (i << 9);
    float2 k2 = kp[n];
    float ix = (k2.x + 1.f) * (WW * 0.5f) - 0.5f;
    float iy = (k2.y + 1.f) * (HH * 0.5f) - 0.5f;
    float x0f = floorf(ix), y0f = floorf(iy);
    float wx = ix - x0f, wy = iy - y0f;
    int x0 = (int)x0f, y0 = (int)y0f;
    float ax0 = (x0 >= 0 && x0 < WW) ? (1.f - wx) : 0.f;
    float ax1 = (x0 + 1 >= 0 && x0 + 1 < WW) ? wx : 0.f;
    float ay0 = (y0 >= 0 && y0 < HH) ? (1.f - wy) : 0.f;
    float ay1 = (y0 + 1 >= 0 && y0 + 1 < HH) ? wy : 0.f;
    int bx = min(max(x0, 0), WW - 2);
    int by = min(max(y0, 0), HH - 2);
    float a0 = 0.f, a1 = 0.f, c0 = 0.f, c1 = 0.f;
    if (x0 == bx) a0 += ax0; else if (x0 == bx + 1) a1 += ax0;
    if (x0 + 1 == bx) a0 += ax1; else if (x0 + 1 == bx + 1) a1 += ax1;
    if (y0 == by) c0 += ay0; else if (y0 == by + 1) c1 += ay0;
    if (y0 + 1 == by) c0 += ay1; else if (y0 + 1 == by + 1) c1 += ay1;
    base[i] = by * WW + bx;
    wt[i] = make_float4(a0 * c0, a1 * c0, a0 * c1, a1 * c1);
  }
  bf16x8 res[8];  // res[i][p] : point i, plane p
#pragma unroll
  for (int p = 0; p < 8; ++p) {
    float* bcur = buf[p & 1];
    float4* b4 = (float4*)bcur;
    // ds_write current plane from its register set (vmcnt wait is register-
    // precise: only this plane's loads, which had 2 planes of time in flight)
    if (p & 1) {
#pragma unroll
      for (int q = 0; q < 8; ++q) b4[t + 512 * q] = r1[q];
    } else {
#pragma unroll
      for (int q = 0; q < 8; ++q) b4[t + 512 * q] = r0[q];
    }
    __syncthreads();  // nothing else in flight here -> no hidden vmcnt stall
    // refill the just-freed register set with plane p+2
    if (p + 2 < 8) {
      if (p & 1) {
#pragma unroll
        for (int q = 0; q < 8; ++q) r1[q] = x4[(p + 2) * 4096 + t + 512 * q];
      } else {
#pragma unroll
        for (int q = 0; q < 8; ++q) r0[q] = x4[(p + 2) * 4096 + t + 512 * q];
      }
    }
    // gather this plane (overlaps the in-flight loads above)
#pragma unroll
    for (int i = 0; i < 8; ++i) {
      int bs = base[i];
      float4 w = wt[i];
      float v = bcur[bs] * w.x + bcur[bs + 1] * w.y
              + bcur[bs + WW] * w.z + bcur[bs + WW + 1] * w.w;
      res[i][p] = (__bf16)v;
    }
  }
  // --- coalesced stores: one dwordx4 per point (8 planes packed) ---
#pragma unroll
  for (int i = 0; i < 8; ++i) {
    int n = t + (i << 9);
    size_t a16 = ((size_t)b << 17) + ((size_t)(n >> 4) << 9)
               + ((size_t)(g >> 2) << 6) + ((size_t)(g & 3) << 4) + (n & 15);
    *(bf16x8*)(descf + (a16 << 3)) = res[i];
  }
}

// MFMA GEMM + bias + L2-normalize (unchanged from R3).
// 512 blocks x 256 thr (4 waves). Wave = one ntile (16 n) x full 128 e.
__global__ __launch_bounds__(256) void gemm_norm_kernel(
    const __bf16* __restrict__ descf, const __bf16* __restrict__ Wf,
    const float* __restrict__ bias, float* __restrict__ out) {
  __shared__ __bf16 wlds[8 * 8 * 64 * 8];  // 64 KiB
  int t = threadIdx.x;
  {
    const float4* src = (const float4*)Wf;
    float4* d = (float4*)wlds;
#pragma unroll
    for (int i = 0; i < 16; ++i) d[t + 256 * i] = src[t + 256 * i];
  }
  __syncthreads();
  int blk = blockIdx.x;  // b*64 + nblk
  int b = blk >> 6;
  int wave = t >> 6, lane = t & 63;
  int ntile = ((blk & 63) << 2) + wave;  // 0..255 within b
  const bf16x8* bsrc =
      (const bf16x8*)(descf + ((size_t)b << 20) + ((size_t)ntile << 12));
  bf16x8 bfrag[8];
#pragma unroll
  for (int k = 0; k < 8; ++k) bfrag[k] = bsrc[k * 64 + lane];  // prefetch all B
  const bf16x8* alds = (const bf16x8*)wlds;
  f32x4 acc[8];
#pragma unroll
  for (int e = 0; e < 8; ++e) acc[e] = (f32x4)(0.f);
#pragma unroll
  for (int k = 0; k < 8; ++k) {
#pragma unroll
    for (int e = 0; e < 8; ++e) {
      bf16x8 a = alds[(k * 8 + e) * 64 + lane];
      acc[e] = __builtin_amdgcn_mfma_f32_16x16x32_bf16(a, bfrag[k], acc[e], 0, 0, 0);
    }
  }
  // epilogue: D col=lane&15 -> n, row=quad*4+reg -> e (+16*etile)
  int quad = lane >> 4, col = lane & 15;
  int n = ntile * 16 + col;
  float s = 0.f;
  float4 av[8];
#pragma unroll
  for (int e = 0; e < 8; ++e) {
    float4 bi = *(const float4*)(bias + e * 16 + quad * 4);
    float4 v = make_float4(acc[e][0] + bi.x, acc[e][1] + bi.y,
                           acc[e][2] + bi.z, acc[e][3] + bi.w);
    av[e] = v;
    s += v.x * v.x + v.y * v.y + v.z * v.z + v.w * v.w;
  }
  s += __shfl_xor(s, 16);
  s += __shfl_xor(s, 32);
  float inv = 1.f / fmaxf(sqrtf(s), 1e-12f);
  float4* out4 = (float4*)out + (((size_t)(b * NN + n)) << 5) + quad;
#pragma unroll
  for (int e = 0; e < 8; ++e)
    out4[e * 4] = make_float4(av[e].x * inv, av[e].y * inv,
                              av[e].z * inv, av[e].w * inv);
}

// Correctness fallback if ws_size is too small: one block per point.
__global__ __launch_bounds__(128) void fused_fallback(
    const float* __restrict__ x, const float* __restrict__ kpts,
    const float* __restrict__ W, const float* __restrict__ bias,
    float* __restrict__ out) {
  __shared__ float dsc[CC];
  __shared__ float sred[2];
  int blk = blockIdx.x;  // b*NN + n
  int b = blk >> 12;
  float kx = kpts[2 * blk], ky = kpts[2 * blk + 1];
  float ix = (kx + 1.f) * (WW * 0.5f) - 0.5f;
  float iy = (ky + 1.f) * (HH * 0.5f) - 0.5f;
  float x0f = floorf(ix), y0f = floorf(iy);
  float wx = ix - x0f, wy = iy - y0f;
  int x0 = (int)x0f, y0 = (int)y0f;
  float ax0 = (x0 >= 0 && x0 < WW) ? (1.f - wx) : 0.f;
  float ax1 = (x0 + 1 >= 0 && x0 + 1 < WW) ? wx : 0.f;
  float ay0 = (y0 >= 0 && y0 < HH) ? (1.f - wy) : 0.f;
  float ay1 = (y0 + 1 >= 0 && y0 + 1 < HH) ? wy : 0.f;
  int bx = min(max(x0, 0), WW - 2);
  int by = min(max(y0, 0), HH - 2);
  float a0 = 0.f, a1 = 0.f, r0 = 0.f, r1 = 0.f;
  if (x0 == bx) a0 += ax0; else if (x0 == bx + 1) a1 += ax0;
  if (x0 + 1 == bx) a0 += ax1; else if (x0 + 1 == bx + 1) a1 += ax1;
  if (y0 == by) r0 += ay0; else if (y0 == by + 1) r1 += ay0;
  if (y0 + 1 == by) r0 += ay1; else if (y0 + 1 == by + 1) r1 += ay1;
  int base = by * WW + bx;
  float w00 = a0 * r0, w10 = a1 * r0, w01 = a0 * r1, w11 = a1 * r1;
  int t = threadIdx.x;
  const float* src = x + ((size_t)b << 22);
  for (int c = t; c < CC; c += 128) {
    const float* p = src + ((size_t)c << 14);
    dsc[c] = p[base] * w00 + p[base + 1] * w10 + p[base + WW] * w01 + p[base + WW + 1] * w11;
  }
  __syncthreads();
  float acc = bias[t];
  const float* wr = W + t * CC;
  for (int c = 0; c < CC; ++c) acc += wr[c] * dsc[c];
  float s = acc * acc;
  for (int m = 1; m < 64; m <<= 1) s += __shfl_xor(s, m);
  if ((t & 63) == 0) sred[t >> 6] = s;
  __syncthreads();
  float tot = sred[0] + sred[1];
  float inv = 1.f / fmaxf(sqrtf(tot), 1e-12f);
  out[((size_t)blk << 7) + t] = acc * inv;
}

extern "C" void kernel_launch(void* const* d_in, const int* in_sizes, int n_in,
                              void* d_out, int out_size, void* d_ws, size_t ws_size,
                              hipStream_t stream) {
  const float* x    = (const float*)d_in[0];
  const float* kpts = (const float*)d_in[1];
  const float* W    = (const float*)d_in[2];
  const float* bias = (const float*)d_in[3];
  float* out = (float*)d_out;
  if (ws_size >= WS_NEED) {
    char* ws = (char*)d_ws;
    __bf16* Wf    = (__bf16*)(ws + WF_OFF);
    __bf16* descf = (__bf16*)(ws + DESCF_OFF);
    gather_kernel<<<BB * 32, 512, 0, stream>>>(x, kpts, W, descf, Wf);
    gemm_norm_kernel<<<BB * (NN / 64), 256, 0, stream>>>(descf, Wf, bias, out);
  } else {
    fused_fallback<<<BB * NN, 128, 0, stream>>>(x, kpts, W, bias, out);
  }
}

// Round 5
// 210.212 us; speedup vs baseline: 1.2356x; 1.2356x over previous
//
#include <hip/hip_runtime.h>
#include <hip/hip_bf16.h>
#include <math.h>

#define BB 8
#define CC 256
#define HH 128
#define WW 128
#define NN 4096
#define EE 128

typedef __bf16 bf16x8 __attribute__((ext_vector_type(8)));
typedef __bf16 bf16x4 __attribute__((ext_vector_type(4)));
typedef float f32x4 __attribute__((ext_vector_type(4)));

// ---- workspace layout (bytes) ----
#define WF_OFF    0          // __bf16[8][8][64][8]        = 64 KiB  (W, A-frag order)
#define DESCF_OFF 65536      // __bf16[BB][256][8][64][8]  = 16 MiB  (desc, B-frag order)
#define WS_NEED   (65536ull + 16777216ull)

// Async HBM->LDS, 16 B per lane. LDS dest = wave-uniform base + lane*16.
__device__ __forceinline__ void async_copy16(const float* g, float* l) {
  __builtin_amdgcn_global_load_lds(
      (const __attribute__((address_space(1))) void*)g,
      (__attribute__((address_space(3))) void*)l, 16, 0, 0);
}

// Gather v3: 512 blocks (2/CU), 64 KiB LDS, 4 planes per block.
// Plane staged via global_load_lds (no VGPR round-trip -> no spills).
// Per-point results for the 4 planes packed in bf16x4 -> 8 B stores in exact
// MFMA B-fragment order. Bilinear coefs computed in-kernel; Wf emitted by
// blocks 0..255 as a side job.
__global__ __launch_bounds__(512, 4) void gather_kernel(
    const float* __restrict__ x, const float* __restrict__ kpts,
    const float* __restrict__ W, __bf16* __restrict__ descf,
    __bf16* __restrict__ Wf) {
  __shared__ float plane[HH * WW];    // 64 KiB
  int blk = blockIdx.x;               // b*64 + g ; planes c = g*4 .. g*4+3
  int b = blk >> 6, g = blk & 63;
  int t = threadIdx.x;
  int w = t >> 6, lane = t & 63;
  const float* xg = x + ((size_t)((b << 8) + (g << 2)) << 14);  // 4 planes
  // kick off plane 0 staging immediately
  {
    const float* gs = xg + w * 2048 + lane * 4;
    float* ls = plane + w * 2048;
#pragma unroll
    for (int i = 0; i < 8; ++i) async_copy16(gs + i * 256, ls + i * 256);
  }
  // --- W fragment side job (overlaps staging) ---
  if (blk < 256 && t < 128) {
    int i = (blk << 7) + t;
    int j = i & 7, ln = (i >> 3) & 63, etile = (i >> 9) & 7, kstep = (i >> 12) & 7;
    Wf[i] = (__bf16)W[(etile * 16 + (ln & 15)) * CC + kstep * 32 + ((ln >> 4) << 3) + j];
  }
  // --- bilinear coefs for this thread's 8 points (overlaps staging) ---
  int base[8];
  float4 wt[8];
  const float2* kp = (const float2*)(kpts + ((size_t)(b * NN) << 1));
#pragma unroll
  for (int i = 0; i < 8; ++i) {
    int n = t + (i << 9);
    float2 k2 = kp[n];
    float ix = (k2.x + 1.f) * (WW * 0.5f) - 0.5f;
    float iy = (k2.y + 1.f) * (HH * 0.5f) - 0.5f;
    float x0f = floorf(ix), y0f = floorf(iy);
    float wx = ix - x0f, wy = iy - y0f;
    int x0 = (int)x0f, y0 = (int)y0f;
    float ax0 = (x0 >= 0 && x0 < WW) ? (1.f - wx) : 0.f;
    float ax1 = (x0 + 1 >= 0 && x0 + 1 < WW) ? wx : 0.f;
    float ay0 = (y0 >= 0 && y0 < HH) ? (1.f - wy) : 0.f;
    float ay1 = (y0 + 1 >= 0 && y0 + 1 < HH) ? wy : 0.f;
    int bx = min(max(x0, 0), WW - 2);
    int by = min(max(y0, 0), HH - 2);
    float a0 = 0.f, a1 = 0.f, c0 = 0.f, c1 = 0.f;
    if (x0 == bx) a0 += ax0; else if (x0 == bx + 1) a1 += ax0;
    if (x0 + 1 == bx) a0 += ax1; else if (x0 + 1 == bx + 1) a1 += ax1;
    if (y0 == by) c0 += ay0; else if (y0 == by + 1) c1 += ay0;
    if (y0 + 1 == by) c0 += ay1; else if (y0 + 1 == by + 1) c1 += ay1;
    base[i] = by * WW + bx;
    wt[i] = make_float4(a0 * c0, a1 * c0, a0 * c1, a1 * c1);
  }
  bf16x4 res[8];  // res[i][p] : point i, plane p (4 planes this block)
#pragma unroll
  for (int p = 0; p < 4; ++p) {
    __syncthreads();  // vmcnt(0) drain: plane p fully in LDS
#pragma unroll
    for (int i = 0; i < 8; ++i) {
      int bs = base[i];
      float4 ww = wt[i];
      float v = plane[bs] * ww.x + plane[bs + 1] * ww.y
              + plane[bs + WW] * ww.z + plane[bs + WW + 1] * ww.w;
      res[i][p] = (__bf16)v;
    }
    __syncthreads();  // all gathers done before overwrite
    if (p < 3) {
      const float* gs = xg + (p + 1) * 16384 + w * 2048 + lane * 4;
      float* ls = plane + w * 2048;
#pragma unroll
      for (int i = 0; i < 8; ++i) async_copy16(gs + i * 256, ls + i * 256);
    }
  }
  // --- stores: 8 B per point, B-frag order ---
  int c0i = g << 2;
  int kstep = c0i >> 5, quad = (c0i >> 3) & 3, j0 = c0i & 7;
#pragma unroll
  for (int i = 0; i < 8; ++i) {
    int n = t + (i << 9);
    size_t off = (((size_t)((b << 8) + (n >> 4))) << 12)
               + ((size_t)kstep << 9) + ((size_t)quad << 7) + ((size_t)(n & 15) << 3) + j0;
    *(bf16x4*)(descf + off) = res[i];
  }
}

// MFMA GEMM + bias + L2-normalize (unchanged from R3).
// 512 blocks x 256 thr (4 waves). Wave = one ntile (16 n) x full 128 e.
__global__ __launch_bounds__(256) void gemm_norm_kernel(
    const __bf16* __restrict__ descf, const __bf16* __restrict__ Wf,
    const float* __restrict__ bias, float* __restrict__ out) {
  __shared__ __bf16 wlds[8 * 8 * 64 * 8];  // 64 KiB
  int t = threadIdx.x;
  {
    const float4* src = (const float4*)Wf;
    float4* d = (float4*)wlds;
#pragma unroll
    for (int i = 0; i < 16; ++i) d[t + 256 * i] = src[t + 256 * i];
  }
  __syncthreads();
  int blk = blockIdx.x;  // b*64 + nblk
  int b = blk >> 6;
  int wave = t >> 6, lane = t & 63;
  int ntile = ((blk & 63) << 2) + wave;  // 0..255 within b
  const bf16x8* bsrc =
      (const bf16x8*)(descf + ((size_t)b << 20) + ((size_t)ntile << 12));
  bf16x8 bfrag[8];
#pragma unroll
  for (int k = 0; k < 8; ++k) bfrag[k] = bsrc[k * 64 + lane];  // prefetch all B
  const bf16x8* alds = (const bf16x8*)wlds;
  f32x4 acc[8];
#pragma unroll
  for (int e = 0; e < 8; ++e) acc[e] = (f32x4)(0.f);
#pragma unroll
  for (int k = 0; k < 8; ++k) {
#pragma unroll
    for (int e = 0; e < 8; ++e) {
      bf16x8 a = alds[(k * 8 + e) * 64 + lane];
      acc[e] = __builtin_amdgcn_mfma_f32_16x16x32_bf16(a, bfrag[k], acc[e], 0, 0, 0);
    }
  }
  // epilogue: D col=lane&15 -> n, row=quad*4+reg -> e (+16*etile)
  int quad = lane >> 4, col = lane & 15;
  int n = ntile * 16 + col;
  float s = 0.f;
  float4 av[8];
#pragma unroll
  for (int e = 0; e < 8; ++e) {
    float4 bi = *(const float4*)(bias + e * 16 + quad * 4);
    float4 v = make_float4(acc[e][0] + bi.x, acc[e][1] + bi.y,
                           acc[e][2] + bi.z, acc[e][3] + bi.w);
    av[e] = v;
    s += v.x * v.x + v.y * v.y + v.z * v.z + v.w * v.w;
  }
  s += __shfl_xor(s, 16);
  s += __shfl_xor(s, 32);
  float inv = 1.f / fmaxf(sqrtf(s), 1e-12f);
  float4* out4 = (float4*)out + (((size_t)(b * NN + n)) << 5) + quad;
#pragma unroll
  for (int e = 0; e < 8; ++e)
    out4[e * 4] = make_float4(av[e].x * inv, av[e].y * inv,
                              av[e].z * inv, av[e].w * inv);
}

// Correctness fallback if ws_size is too small: one block per point.
__global__ __launch_bounds__(128) void fused_fallback(
    const float* __restrict__ x, const float* __restrict__ kpts,
    const float* __restrict__ W, const float* __restrict__ bias,
    float* __restrict__ out) {
  __shared__ float dsc[CC];
  __shared__ float sred[2];
  int blk = blockIdx.x;  // b*NN + n
  int b = blk >> 12;
  float kx = kpts[2 * blk], ky = kpts[2 * blk + 1];
  float ix = (kx + 1.f) * (WW * 0.5f) - 0.5f;
  float iy = (ky + 1.f) * (HH * 0.5f) - 0.5f;
  float x0f = floorf(ix), y0f = floorf(iy);
  float wx = ix - x0f, wy = iy - y0f;
  int x0 = (int)x0f, y0 = (int)y0f;
  float ax0 = (x0 >= 0 && x0 < WW) ? (1.f - wx) : 0.f;
  float ax1 = (x0 + 1 >= 0 && x0 + 1 < WW) ? wx : 0.f;
  float ay0 = (y0 >= 0 && y0 < HH) ? (1.f - wy) : 0.f;
  float ay1 = (y0 + 1 >= 0 && y0 + 1 < HH) ? wy : 0.f;
  int bx = min(max(x0, 0), WW - 2);
  int by = min(max(y0, 0), HH - 2);
  float a0 = 0.f, a1 = 0.f, r0 = 0.f, r1 = 0.f;
  if (x0 == bx) a0 += ax0; else if (x0 == bx + 1) a1 += ax0;
  if (x0 + 1 == bx) a0 += ax1; else if (x0 + 1 == bx + 1) a1 += ax1;
  if (y0 == by) r0 += ay0; else if (y0 == by + 1) r1 += ay0;
  if (y0 + 1 == by) r0 += ay1; else if (y0 + 1 == by + 1) r1 += ay1;
  int base = by * WW + bx;
  float w00 = a0 * r0, w10 = a1 * r0, w01 = a0 * r1, w11 = a1 * r1;
  int t = threadIdx.x;
  const float* src = x + ((size_t)b << 22);
  for (int c = t; c < CC; c += 128) {
    const float* p = src + ((size_t)c << 14);
    dsc[c] = p[base] * w00 + p[base + 1] * w10 + p[base + WW] * w01 + p[base + WW + 1] * w11;
  }
  __syncthreads();
  float acc = bias[t];
  const float* wr = W + t * CC;
  for (int c = 0; c < CC; ++c) acc += wr[c] * dsc[c];
  float s = acc * acc;
  for (int m = 1; m < 64; m <<= 1) s += __shfl_xor(s, m);
  if ((t & 63) == 0) sred[t >> 6] = s;
  __syncthreads();
  float tot = sred[0] + sred[1];
  float inv = 1.f / fmaxf(sqrtf(tot), 1e-12f);
  out[((size_t)blk << 7) + t] = acc * inv;
}

extern "C" void kernel_launch(void* const* d_in, const int* in_sizes, int n_in,
                              void* d_out, int out_size, void* d_ws, size_t ws_size,
                              hipStream_t stream) {
  const float* x    = (const float*)d_in[0];
  const float* kpts = (const float*)d_in[1];
  const float* W    = (const float*)d_in[2];
  const float* bias = (const float*)d_in[3];
  float* out = (float*)d_out;
  if (ws_size >= WS_NEED) {
    char* ws = (char*)d_ws;
    __bf16* Wf    = (__bf16*)(ws + WF_OFF);
    __bf16* descf = (__bf16*)(ws + DESCF_OFF);
    gather_kernel<<<BB * 64, 512, 0, stream>>>(x, kpts, W, descf, Wf);
    gemm_norm_kernel<<<BB * (NN / 64), 256, 0, stream>>>(descf, Wf, bias, out);
  } else {
    fused_fallback<<<BB * NN, 128, 0, stream>>>(x, kpts, W, bias, out);
  }
}

// Round 6
// 210.092 us; speedup vs baseline: 1.2363x; 1.0006x over previous
//
#include <hip/hip_runtime.h>
#include <hip/hip_bf16.h>
#include <math.h>

#define BB 8
#define CC 256
#define HH 128
#define WW 128
#define NN 4096
#define EE 128

typedef __bf16 bf16x8 __attribute__((ext_vector_type(8)));
typedef float f32x4 __attribute__((ext_vector_type(4)));

// ---- workspace layout (bytes) ----
#define WF_OFF    0          // __bf16[8][8][64][8]        = 64 KiB  (W, A-frag order)
#define DESCF_OFF 65536      // __bf16[BB][256][8][64][8]  = 16 MiB  (desc, B-frag order)
#define WS_NEED   (65536ull + 16777216ull)

// Async HBM->LDS, 16 B per lane. LDS dest = wave-uniform base + lane*16.
__device__ __forceinline__ void async_copy16(const float* g, float* l) {
  __builtin_amdgcn_global_load_lds(
      (const __attribute__((address_space(1))) void*)g,
      (__attribute__((address_space(3))) void*)l, 16, 0, 0);
}

// Gather v4: 256 blocks (1/CU), 128 KiB LDS = two 64 KiB plane buffers,
// 8 planes per block. Double-buffered: loads for plane p+1 (global_load_lds,
// no VGPR round trip) fly while plane p is gathered. Results for the 8
// planes pack into one bf16x8 per point -> coalesced 16 B stores in exact
// MFMA B-fragment order. Bilinear coefs computed in-kernel; Wf emitted as a
// side job.
__global__ __launch_bounds__(512) void gather_kernel(
    const float* __restrict__ x, const float* __restrict__ kpts,
    const float* __restrict__ W, __bf16* __restrict__ descf,
    __bf16* __restrict__ Wf) {
  __shared__ float buf[2][HH * WW];   // 128 KiB
  int blk = blockIdx.x;               // b*32 + g ; planes c = g*8 .. g*8+7
  int b = blk >> 5, g = blk & 31;
  int t = threadIdx.x;
  int w = t >> 6, lane = t & 63;
  const float* xg = x + ((size_t)((b << 8) + (g << 3)) << 14);  // 8 planes
  // issue plane 0 -> buf[0]
  {
    const float* gs = xg + w * 2048 + lane * 4;
    float* ls = buf[0] + w * 2048;
#pragma unroll
    for (int i = 0; i < 8; ++i) async_copy16(gs + i * 256, ls + i * 256);
  }
  // --- W fragment side job (overlaps staging) ---
  if (t < 128) {
    int i = (blk << 7) + t;
    int j = i & 7, ln = (i >> 3) & 63, etile = (i >> 9) & 7, kstep = (i >> 12) & 7;
    Wf[i] = (__bf16)W[(etile * 16 + (ln & 15)) * CC + kstep * 32 + ((ln >> 4) << 3) + j];
  }
  // --- bilinear coefs for this thread's 8 points (overlaps staging) ---
  int base[8];
  float4 wt[8];
  const float2* kp = (const float2*)(kpts + ((size_t)(b * NN) << 1));
#pragma unroll
  for (int i = 0; i < 8; ++i) {
    int n = t + (i << 9);
    float2 k2 = kp[n];
    float ix = (k2.x + 1.f) * (WW * 0.5f) - 0.5f;
    float iy = (k2.y + 1.f) * (HH * 0.5f) - 0.5f;
    float x0f = floorf(ix), y0f = floorf(iy);
    float wx = ix - x0f, wy = iy - y0f;
    int x0 = (int)x0f, y0 = (int)y0f;
    float ax0 = (x0 >= 0 && x0 < WW) ? (1.f - wx) : 0.f;
    float ax1 = (x0 + 1 >= 0 && x0 + 1 < WW) ? wx : 0.f;
    float ay0 = (y0 >= 0 && y0 < HH) ? (1.f - wy) : 0.f;
    float ay1 = (y0 + 1 >= 0 && y0 + 1 < HH) ? wy : 0.f;
    int bx = min(max(x0, 0), WW - 2);
    int by = min(max(y0, 0), HH - 2);
    float a0 = 0.f, a1 = 0.f, c0 = 0.f, c1 = 0.f;
    if (x0 == bx) a0 += ax0; else if (x0 == bx + 1) a1 += ax0;
    if (x0 + 1 == bx) a0 += ax1; else if (x0 + 1 == bx + 1) a1 += ax1;
    if (y0 == by) c0 += ay0; else if (y0 == by + 1) c1 += ay0;
    if (y0 + 1 == by) c0 += ay1; else if (y0 + 1 == by + 1) c1 += ay1;
    base[i] = by * WW + bx;
    wt[i] = make_float4(a0 * c0, a1 * c0, a0 * c1, a1 * c1);
  }
  bf16x8 res[8];  // res[i][p] : point i, plane p
#pragma unroll
  for (int p = 0; p < 8; ++p) {
    __syncthreads();  // drains loads for plane p (they were issued last iter)
    if (p < 7) {      // issue loads p+1 into the other buffer; they fly
      const float* gs = xg + (p + 1) * 16384 + w * 2048 + lane * 4;
      float* ls = buf[(p + 1) & 1] + w * 2048;
#pragma unroll
      for (int i = 0; i < 8; ++i) async_copy16(gs + i * 256, ls + i * 256);
    }
    const float* bcur = buf[p & 1];
#pragma unroll
    for (int i = 0; i < 8; ++i) {
      int bs = base[i];
      float4 ww = wt[i];
      float v = bcur[bs] * ww.x + bcur[bs + 1] * ww.y
              + bcur[bs + WW] * ww.z + bcur[bs + WW + 1] * ww.w;
      res[i][p] = (__bf16)v;
    }
  }
  // --- stores: 16 B per point (8 planes = full j index), B-frag order ---
  // c = g*8 + p -> kstep = g>>2, quad = g&3, j = p
  int kstep = g >> 2, quad = g & 3;
#pragma unroll
  for (int i = 0; i < 8; ++i) {
    int n = t + (i << 9);
    size_t off = (((size_t)((b << 8) + (n >> 4))) << 12)
               + ((size_t)kstep << 9) + ((size_t)quad << 7) + ((size_t)(n & 15) << 3);
    *(bf16x8*)(descf + off) = res[i];
  }
}

// MFMA GEMM + bias + L2-normalize.
// 512 blocks x 256 thr (4 waves). Wave = one ntile (16 n) x full 128 e.
// Epilogue routes through LDS so global stores are 1 KiB contiguous.
__global__ __launch_bounds__(256) void gemm_norm_kernel(
    const __bf16* __restrict__ descf, const __bf16* __restrict__ Wf,
    const float* __restrict__ bias, float* __restrict__ out) {
  __shared__ __bf16 wlds[8 * 8 * 64 * 8];  // 64 KiB (reused as f4 scratch)
  int t = threadIdx.x;
  {
    const float4* src = (const float4*)Wf;
    float4* d = (float4*)wlds;
#pragma unroll
    for (int i = 0; i < 16; ++i) d[t + 256 * i] = src[t + 256 * i];
  }
  __syncthreads();
  int blk = blockIdx.x;  // b*64 + nblk
  int b = blk >> 6;
  int wave = t >> 6, lane = t & 63;
  int ntile = ((blk & 63) << 2) + wave;  // 0..255 within b
  const bf16x8* bsrc =
      (const bf16x8*)(descf + ((size_t)b << 20) + ((size_t)ntile << 12));
  bf16x8 bfrag[8];
#pragma unroll
  for (int k = 0; k < 8; ++k) bfrag[k] = bsrc[k * 64 + lane];  // prefetch all B
  const bf16x8* alds = (const bf16x8*)wlds;
  f32x4 acc[8];
#pragma unroll
  for (int e = 0; e < 8; ++e) acc[e] = (f32x4)(0.f);
#pragma unroll
  for (int k = 0; k < 8; ++k) {
#pragma unroll
    for (int e = 0; e < 8; ++e) {
      bf16x8 a = alds[(k * 8 + e) * 64 + lane];
      acc[e] = __builtin_amdgcn_mfma_f32_16x16x32_bf16(a, bfrag[k], acc[e], 0, 0, 0);
    }
  }
  // D layout: col=lane&15 -> n, row=quad*4+reg -> e (+16*etile)
  int quad = lane >> 4, col = lane & 15;
  float s = 0.f;
  float4 av[8];
#pragma unroll
  for (int e = 0; e < 8; ++e) {
    float4 bi = *(const float4*)(bias + e * 16 + quad * 4);
    float4 v = make_float4(acc[e][0] + bi.x, acc[e][1] + bi.y,
                           acc[e][2] + bi.z, acc[e][3] + bi.w);
    av[e] = v;
    s += v.x * v.x + v.y * v.y + v.z * v.z + v.w * v.w;
  }
  s += __shfl_xor(s, 16);
  s += __shfl_xor(s, 32);
  float inv = 1.f / fmaxf(sqrtf(s), 1e-12f);
  // --- LDS transpose: sc[wave][col][e*4+quad] (33-f4 pad per col) ---
  __syncthreads();  // K-loop ds_reads done; wlds reusable
  float4* sc = (float4*)wlds;
  int sbase = wave * 528 + col * 33 + quad;
#pragma unroll
  for (int e = 0; e < 8; ++e)
    sc[sbase + e * 4] = make_float4(av[e].x * inv, av[e].y * inv,
                                    av[e].z * inv, av[e].w * inv);
  __syncthreads();
  // read back n-major, store 1 KiB contiguous per instr (2 n-rows)
  int e4 = lane & 31, dn = lane >> 5;
  float4* ob = (float4*)out + (((size_t)(b * NN + ntile * 16)) << 5);
#pragma unroll
  for (int i = 0; i < 8; ++i) {
    int nn = 2 * i + dn;
    ob[((size_t)nn << 5) + e4] = sc[wave * 528 + nn * 33 + e4];
  }
}

// Correctness fallback if ws_size is too small: one block per point.
__global__ __launch_bounds__(128) void fused_fallback(
    const float* __restrict__ x, const float* __restrict__ kpts,
    const float* __restrict__ W, const float* __restrict__ bias,
    float* __restrict__ out) {
  __shared__ float dsc[CC];
  __shared__ float sred[2];
  int blk = blockIdx.x;  // b*NN + n
  int b = blk >> 12;
  float kx = kpts[2 * blk], ky = kpts[2 * blk + 1];
  float ix = (kx + 1.f) * (WW * 0.5f) - 0.5f;
  float iy = (ky + 1.f) * (HH * 0.5f) - 0.5f;
  float x0f = floorf(ix), y0f = floorf(iy);
  float wx = ix - x0f, wy = iy - y0f;
  int x0 = (int)x0f, y0 = (int)y0f;
  float ax0 = (x0 >= 0 && x0 < WW) ? (1.f - wx) : 0.f;
  float ax1 = (x0 + 1 >= 0 && x0 + 1 < WW) ? wx : 0.f;
  float ay0 = (y0 >= 0 && y0 < HH) ? (1.f - wy) : 0.f;
  float ay1 = (y0 + 1 >= 0 && y0 + 1 < HH) ? wy : 0.f;
  int bx = min(max(x0, 0), WW - 2);
  int by = min(max(y0, 0), HH - 2);
  float a0 = 0.f, a1 = 0.f, r0 = 0.f, r1 = 0.f;
  if (x0 == bx) a0 += ax0; else if (x0 == bx + 1) a1 += ax0;
  if (x0 + 1 == bx) a0 += ax1; else if (x0 + 1 == bx + 1) a1 += ax1;
  if (y0 == by) r0 += ay0; else if (y0 == by + 1) r1 += ay0;
  if (y0 + 1 == by) r0 += ay1; else if (y0 + 1 == by + 1) r1 += ay1;
  int base = by * WW + bx;
  float w00 = a0 * r0, w10 = a1 * r0, w01 = a0 * r1, w11 = a1 * r1;
  int t = threadIdx.x;
  const float* src = x + ((size_t)b << 22);
  for (int c = t; c < CC; c += 128) {
    const float* p = src + ((size_t)c << 14);
    dsc[c] = p[base] * w00 + p[base + 1] * w10 + p[base + WW] * w01 + p[base + WW + 1] * w11;
  }
  __syncthreads();
  float acc = bias[t];
  const float* wr = W + t * CC;
  for (int c = 0; c < CC; ++c) acc += wr[c] * dsc[c];
  float s = acc * acc;
  for (int m = 1; m < 64; m <<= 1) s += __shfl_xor(s, m);
  if ((t & 63) == 0) sred[t >> 6] = s;
  __syncthreads();
  float tot = sred[0] + sred[1];
  float inv = 1.f / fmaxf(sqrtf(tot), 1e-12f);
  out[((size_t)blk << 7) + t] = acc * inv;
}

extern "C" void kernel_launch(void* const* d_in, const int* in_sizes, int n_in,
                              void* d_out, int out_size, void* d_ws, size_t ws_size,
                              hipStream_t stream) {
  const float* x    = (const float*)d_in[0];
  const float* kpts = (const float*)d_in[1];
  const float* W    = (const float*)d_in[2];
  const float* bias = (const float*)d_in[3];
  float* out = (float*)d_out;
  if (ws_size >= WS_NEED) {
    char* ws = (char*)d_ws;
    __bf16* Wf    = (__bf16*)(ws + WF_OFF);
    __bf16* descf = (__bf16*)(ws + DESCF_OFF);
    gather_kernel<<<BB * 32, 512, 0, stream>>>(x, kpts, W, descf, Wf);
    gemm_norm_kernel<<<BB * (NN / 64), 256, 0, stream>>>(descf, Wf, bias, out);
  } else {
    fused_fallback<<<BB * NN, 128, 0, stream>>>(x, kpts, W, bias, out);
  }
}